// Round 13
// baseline (186.312 us; speedup 1.0000x reference)
//
#include <hip/hip_runtime.h>

// B=4, S=2048, D=1024, H=16, HS=64. Full bf16-MFMA pipeline.
// Workspace layout (needs ~104 MiB):
//   Xb     @ 0         : x as bf16            [8192][1024]   16 MiB
//   WqkvT  @ 16777216  : qkv weights B^T bf16 [3072][1024]    6 MiB
//   WoT    @ 23068672  : Wo^T bf16            [1024][1024]    2 MiB
//   QKV    @ 25165824  : Q|K|V bf16           [8192][3072]   48 MiB
//   VT     @ 75497472  : V^T bf16, kappa-ordered keys  [64bh][64][2048] 16 MiB
//   AttnO  @ 92274688  : attention out bf16   [8192][1024]   16 MiB

typedef __bf16 bf16;
typedef bf16 bf16x8 __attribute__((ext_vector_type(8)));
typedef bf16 bf16x4 __attribute__((ext_vector_type(4)));
typedef float f32x4 __attribute__((ext_vector_type(4)));

__device__ __forceinline__ void gload16(const void* gsrc, void* ldst) {
  __builtin_amdgcn_global_load_lds(
      (const __attribute__((address_space(1))) unsigned int*)gsrc,
      (__attribute__((address_space(3))) unsigned int*)ldst, 16, 0, 0);
}

__device__ __forceinline__ f32x4 mfma16(bf16x8 a, bf16x8 b, f32x4 c) {
  return __builtin_amdgcn_mfma_f32_16x16x32_bf16(a, b, c, 0, 0, 0);
}

// ---------------- pack kernels ----------------
__global__ __launch_bounds__(256) void pack_x_kernel(const float* __restrict__ x,
                                                     bf16* __restrict__ xb) {
  int i = (blockIdx.x * 256 + threadIdx.x) * 4;  // grid sized exactly
  float4 v = *(const float4*)(x + i);
  bf16x4 o;
  o[0] = (bf16)v.x; o[1] = (bf16)v.y; o[2] = (bf16)v.z; o[3] = (bf16)v.w;
  *(bf16x4*)(xb + i) = o;
}

// WT[n][k] = W{q,k,v}[h = (n%1024)/64][k][e = n%64], n in [0,3072)
__global__ __launch_bounds__(256) void pack_wqkv_kernel(const float* __restrict__ Wq,
                                                        const float* __restrict__ Wk,
                                                        const float* __restrict__ Wv,
                                                        bf16* __restrict__ WT) {
  int idx = blockIdx.x * 256 + threadIdx.x;  // 0..3145727
  int n = idx >> 10, k = idx & 1023;
  int sel = n >> 10, nn = n & 1023;
  const float* W = (sel == 0) ? Wq : (sel == 1 ? Wk : Wv);
  int h = nn >> 6, e = nn & 63;
  WT[(size_t)n * 1024 + k] = (bf16)W[h * 65536 + k * 64 + e];
}

// WoT[n][k] = Wo[k][n]
__global__ __launch_bounds__(256) void pack_wo_kernel(const float* __restrict__ Wo,
                                                      bf16* __restrict__ WoT) {
  int idx = blockIdx.x * 256 + threadIdx.x;  // 0..1048575
  int n = idx >> 10, k = idx & 1023;
  WoT[idx] = (bf16)Wo[k * 1024 + n];
}

// ---------------- GEMM v5: deep counted-vmcnt pipeline ----------------
// r12 post-mortem: the 128^2/dbuf structure is latency-bound by its own sync
// (nothing >35% busy). Fix per T3/T4: 3 LDS slots, stage 2 K-tiles ahead,
// steady-state s_waitcnt vmcnt(6) (= 6 loads/tile x 1 future tile in flight),
// never a mid-loop drain; ONE barrier per K-tile. BM=256 BN=128 BK=64,
// 512 threads = 8 waves (4m x 2n), per-wave 64x64 (gemm4's verified
// fragment/swizzle/epilogue math). LDS 144KB -> 1 block/CU, 2 waves/SIMD.
// Hazards: tile t stages slot (t+2)%3 = slot last read in tile t-1,
// separated by the top-of-t barrier; all ds_reads feed same-tile MFMAs so
// lgkm drains before any wave reaches the next barrier.
// n-major-per-XCD mapping: per XCD a 4-m-tile A panel (2MB, L2-resident) +
// concurrent B window ~2MB. Requires M == 8192 (32 m-tiles).
template <bool F32OUT>
__global__ __launch_bounds__(512, 2) void gemm5_kernel(const bf16* __restrict__ A,
                                                       const bf16* __restrict__ BT,
                                                       bf16* __restrict__ Cb,
                                                       float* __restrict__ Cf,
                                                       const float* __restrict__ bias,
                                                       int N, int K) {
  __shared__ bf16 As[3][256 * 64];  // 32KB per slot, chunk-swizzled rows
  __shared__ bf16 Bs[3][128 * 64];  // 16KB per slot
  const int tid = threadIdx.x, lane = tid & 63, wave = tid >> 6;
  const int g = lane >> 4, c = lane & 15;
  const int wr = wave >> 1, wc = wave & 1;  // 4m x 2n waves
  const int bid = blockIdx.x;
  const int xcd = bid & 7, local = bid >> 3;
  const int m0 = (xcd * 4 + (local & 3)) * 256;
  const int n0 = (local >> 2) * 128;

  const int rsub = tid >> 3;         // row within 64-row chunk group
  const int sch = (tid & 7) ^ (rsub & 7);  // pre-swizzled source chunk

#define STAGE5(T, S)                                                        \
  do {                                                                      \
    _Pragma("unroll") for (int j = 0; j < 4; ++j) {                         \
      gload16(A + (size_t)(m0 + j * 64 + rsub) * K + (T)*64 + sch * 8,      \
              (char*)&As[S][0] + j * 8192 + tid * 16);                      \
    }                                                                       \
    _Pragma("unroll") for (int j = 0; j < 2; ++j) {                         \
      gload16(BT + (size_t)(n0 + j * 64 + rsub) * K + (T)*64 + sch * 8,     \
              (char*)&Bs[S][0] + j * 8192 + tid * 16);                      \
    }                                                                       \
  } while (0)

  f32x4 acc[4][4] = {};
  const int nt = K >> 6;  // K-tiles of 64 (16 for K=1024)
  STAGE5(0, 0);
  STAGE5(1, 1);

#pragma unroll 1
  for (int t = 0; t < nt; ++t) {
    const int s = t % 3;
    if (t + 1 < nt) {
      asm volatile("s_waitcnt vmcnt(6)" ::: "memory");  // tile t landed; t+1 in flight
    } else {
      asm volatile("s_waitcnt vmcnt(0)" ::: "memory");
    }
    __builtin_amdgcn_sched_barrier(0);
    __builtin_amdgcn_s_barrier();
    __builtin_amdgcn_sched_barrier(0);
    if (t + 2 < nt) STAGE5(t + 2, (t + 2) % 3);  // 2-ahead, crosses barriers
    bf16x8 af[4][2], bfr[4][2];
#pragma unroll
    for (int m = 0; m < 4; ++m) {
      const int row = wr * 64 + m * 16 + c;
#pragma unroll
      for (int kk = 0; kk < 2; ++kk)
        af[m][kk] = *(const bf16x8*)((const char*)&As[s][0] + row * 128 +
                                     (((kk * 4 + g) ^ (row & 7)) << 4));
    }
#pragma unroll
    for (int n = 0; n < 4; ++n) {
      const int row = wc * 64 + n * 16 + c;
#pragma unroll
      for (int kk = 0; kk < 2; ++kk)
        bfr[n][kk] = *(const bf16x8*)((const char*)&Bs[s][0] + row * 128 +
                                      (((kk * 4 + g) ^ (row & 7)) << 4));
    }
    __builtin_amdgcn_s_setprio(1);
#pragma unroll
    for (int kk = 0; kk < 2; ++kk)
#pragma unroll
      for (int m = 0; m < 4; ++m)
#pragma unroll
        for (int n = 0; n < 4; ++n)
          acc[m][n] = mfma16(af[m][kk], bfr[n][kk], acc[m][n]);
    __builtin_amdgcn_s_setprio(0);
  }
#undef STAGE5
  // epilogue (verified mapping)
#pragma unroll
  for (int m = 0; m < 4; ++m)
#pragma unroll
    for (int n = 0; n < 4; ++n)
#pragma unroll
      for (int i = 0; i < 4; ++i) {
        int row = m0 + wr * 64 + m * 16 + g * 4 + i;
        int col = n0 + wc * 64 + n * 16 + c;
        if (F32OUT)
          Cf[(size_t)row * N + col] = acc[m][n][i] + bias[col];
        else
          Cb[(size_t)row * N + col] = (bf16)acc[m][n][i];
      }
}

// ---------------- V transpose: VT[bh][d][pos] with kappa-ordered keys ------
// Within each 32-key block, storage position p = g*8+j holds key
// kappa(p) = (j<4 ? 4g+j : 16+4g+(j-4)) -- exactly the PV B-frag order, so
// attn's V-read becomes ONE ds_read_b128 per (kss,dn) with even bank spread.
__global__ __launch_bounds__(256) void transpose_v_kernel(const bf16* __restrict__ qkv,
                                                          bf16* __restrict__ vt) {
  __shared__ bf16 tl[64][72];  // stride 144B keeps 16B alignment for b128 stores
  const int tid = threadIdx.x;
  const int st = blockIdx.x, bh = blockIdx.y;
  const int b = bh >> 4, h = bh & 15;
#pragma unroll
  for (int it = 0; it < 2; ++it) {
    int idx = it * 256 + tid;          // 0..511
    int sl = idx >> 3, ch = idx & 7;   // sl 0..63 (s row), ch 0..7 (d chunk)
    bf16x8 v = *(const bf16x8*)(qkv + (size_t)(b * 2048 + st * 64 + sl) * 3072 + 2048 + h * 64 + ch * 8);
    *(bf16x8*)&tl[sl][ch * 8] = v;
  }
  __syncthreads();
#pragma unroll
  for (int it = 0; it < 2; ++it) {
    int idx = it * 256 + tid;
    int d = idx >> 3, ch = idx & 7;    // d 0..63, output chunk 0..7 (8 keys)
    const int blk = ch >> 2, g = ch & 3;  // 32-key block, frag group
    bf16x8 o;
#pragma unroll
    for (int j = 0; j < 8; ++j) {
      int loc = (j < 4) ? (4 * g + j) : (16 + 4 * g + (j - 4));  // kappa
      o[j] = tl[blk * 32 + loc][d];
    }
    *(bf16x8*)(vt + ((size_t)bh * 64 + d) * 2048 + st * 64 + ch * 8) = o;
  }
}

// ---------------- causal flash attention ----------------
// Grid = 512 blocks x 512 threads (8 waves, 16 q-rows/wave), KVBLK=128.
// bh-major XCD mapping (K/V L2-resident per XCD). Block does qt=x then 15-x:
// 17 uniform K-tiles. Double-buffered staging, counted vmcnt. Swapped QK^T
// (mfma(K,Q)): per-lane softmax (q=c), in-lane PV A-frags, row-sum via
// ones-MFMA. Kappa-ordered VT -> single b128 V-reads, conflict-free.
// Tree-max + defer-max (T13, THR=8) cut the softmax VALU/serial chains.
__global__ __launch_bounds__(512, 4) void attn_kernel(const bf16* __restrict__ qkv,
                                                      const bf16* __restrict__ vt,
                                                      bf16* __restrict__ attn_out) {
  __shared__ bf16 Ks[2][128 * 64];   // [key][hd], chunk-swizzled, 16KB each
  __shared__ bf16 Vs[2][64 * 128];   // [d][kpos], chunk-swizzled, 16KB each
  const int tid = threadIdx.x, lane = tid & 63, wave = tid >> 6;
  const int g = lane >> 4, c = lane & 15;
  const int bid = blockIdx.x;
  const int xcd = bid & 7;
  const int x = (bid >> 3) & 7;
  const int bh = (bid >> 6) * 8 + xcd;
  const int b = bh >> 4, h = bh & 15;
  const float SCL = 0.125f * 1.4426950408889634f;  // log2(e) * scale

  bf16x8 ones;
#pragma unroll
  for (int j = 0; j < 8; ++j) ones[j] = (bf16)1.0f;

#define STAGE(KT, BUF)                                                                    \
  do {                                                                                    \
    _Pragma("unroll") for (int t2 = 0; t2 < 2; ++t2) {                                    \
      int o = t2 * 8192 + wave * 1024 + lane * 16; /* 0..16383 */                         \
      int rK = o >> 7, chK = (((o & 127) >> 4) ^ (rK & 7));                               \
      gload16((const char*)qkv +                                                          \
                  ((size_t)(b * 2048 + (KT)*128 + rK) * 3072 + 1024 + h * 64) * 2 +       \
                  (chK << 4),                                                             \
              (char*)Ks[BUF] + o);                                                        \
      int rV = o >> 8, chV = (((o & 255) >> 4) ^ (rV & 7));                               \
      gload16((const char*)vt + (((size_t)bh * 64 + rV) * 2048 + (KT)*128) * 2 +          \
                  (chV << 4),                                                             \
              (char*)Vs[BUF] + o);                                                        \
    }                                                                                     \
  } while (0)

#pragma unroll 1
  for (int ph = 0; ph < 2; ++ph) {
    const int qt = ph ? (15 - x) : x;
    const int qlow = qt * 128 + wave * 16;  // lowest q row of this wave

    bf16x8 qf[2];
#pragma unroll
    for (int kk = 0; kk < 2; ++kk) {
      size_t row = (size_t)(b * 2048 + qlow + c);
      qf[kk] = *(const bf16x8*)(qkv + row * 3072 + h * 64 + kk * 32 + g * 8);
    }

    f32x4 oacc[4] = {};
    f32x4 lacc = {};        // row-sums, oacc layout (q = qlow + 4g+i)
    float mrun = -3.0e38f;  // per-lane: q = qlow + c

    const int nkt = qt + 1;
    STAGE(0, 0);  // prologue
    for (int kt = 0; kt < nkt; ++kt) {
      const int cur = kt & 1;
      if (kt + 1 < nkt) {
        STAGE(kt + 1, cur ^ 1);
        asm volatile("s_waitcnt vmcnt(4)" ::: "memory");  // current tile landed
      } else {
        asm volatile("s_waitcnt vmcnt(0)" ::: "memory");
      }
      __builtin_amdgcn_sched_barrier(0);
      __builtin_amdgcn_s_barrier();
      __builtin_amdgcn_sched_barrier(0);
      // QK^T swapped: sc[n] holds S[key = kt*128+n*16+4g+i][q = qlow+c]
      f32x4 sc[8] = {};
      __builtin_amdgcn_s_setprio(1);
#pragma unroll
      for (int n = 0; n < 8; ++n) {
        int key = n * 16 + c;
#pragma unroll
        for (int kk = 0; kk < 2; ++kk) {
          bf16x8 kf = *(const bf16x8*)((const char*)Ks[cur] + key * 128 +
                                       (((kk * 4 + g) ^ (key & 7)) << 4));
          sc[n] = mfma16(kf, qf[kk], sc[n]);
        }
      }
      __builtin_amdgcn_s_setprio(0);
      const int q = qlow + c;
      if (kt == qt) {  // diagonal tile: causal mask
#pragma unroll
        for (int n = 0; n < 8; ++n)
#pragma unroll
          for (int i = 0; i < 4; ++i)
            sc[n][i] = ((kt * 128 + n * 16 + 4 * g + i) <= q) ? sc[n][i] : -3.0e38f;
      }
      // tree max (depth ~5 instead of a 32-deep serial chain)
      float vmax;
      {
        float a[8];
#pragma unroll
        for (int n = 0; n < 8; ++n)
          a[n] = fmaxf(fmaxf(sc[n][0], sc[n][1]), fmaxf(sc[n][2], sc[n][3]));
        float b0 = fmaxf(a[0], a[1]), b1 = fmaxf(a[2], a[3]);
        float b2 = fmaxf(a[4], a[5]), b3 = fmaxf(a[6], a[7]);
        vmax = fmaxf(fmaxf(b0, b1), fmaxf(b2, b3));
      }
      vmax = fmaxf(vmax, __shfl_xor(vmax, 16));
      vmax = fmaxf(vmax, __shfl_xor(vmax, 32));
      const float mx = vmax * SCL;
      // defer-max (T13): only rescale when the running max grew by >8 in
      // log2 domain; otherwise keep mrun (P bounded by 2^8, fp32-safe).
      if (!__all(mx <= mrun + 8.0f)) {
        const float mnew = fmaxf(mrun, mx);
        const float fs = __builtin_amdgcn_exp2f(mrun - mnew);
        mrun = mnew;
#pragma unroll
        for (int i = 0; i < 4; ++i) {
          float fsb = __shfl(fs, ((lane >> 4) << 2) + i);
          lacc[i] *= fsb;
#pragma unroll
          for (int dn = 0; dn < 4; ++dn) oacc[dn][i] *= fsb;
        }
      }
#pragma unroll
      for (int n = 0; n < 8; ++n)
#pragma unroll
        for (int i = 0; i < 4; ++i)
          sc[n][i] = __builtin_amdgcn_exp2f(fmaf(sc[n][i], SCL, -mrun));
      // pack PV A-frags: key = kss*32 + (j<4 ? 4g+j : 16+4g+(j-4))
      bf16x8 pa[4];
#pragma unroll
      for (int kss = 0; kss < 4; ++kss) {
        bf16x8 t;
#pragma unroll
        for (int j = 0; j < 4; ++j) t[j] = (bf16)sc[2 * kss][j];
#pragma unroll
        for (int j = 0; j < 4; ++j) t[4 + j] = (bf16)sc[2 * kss + 1][j];
        pa[kss] = t;
      }
      // PV + row-sum via ones-MFMA; kappa-ordered Vs -> one b128 per (kss,dn)
      __builtin_amdgcn_s_setprio(1);
#pragma unroll
      for (int kss = 0; kss < 4; ++kss) {
        lacc = mfma16(pa[kss], ones, lacc);
#pragma unroll
        for (int dn = 0; dn < 4; ++dn) {
          const int d = dn * 16 + c;
          bf16x8 vb = *(const bf16x8*)((const char*)Vs[cur] + d * 256 +
                                       (((kss * 4 + g) ^ (d & 7)) << 4));
          oacc[dn] = mfma16(pa[kss], vb, oacc[dn]);
        }
      }
      __builtin_amdgcn_s_setprio(0);
      __builtin_amdgcn_sched_barrier(0);
      __builtin_amdgcn_s_barrier();  // readers done before next-tile overwrite
      __builtin_amdgcn_sched_barrier(0);
    }
    // epilogue: normalize, store bf16 [8192][1024]
#pragma unroll
    for (int i = 0; i < 4; ++i) {
      float inv = __builtin_amdgcn_rcpf(lacc[i]);
      size_t row = (size_t)(b * 2048 + qlow + 4 * g + i);
#pragma unroll
      for (int dn = 0; dn < 4; ++dn)
        attn_out[row * 1024 + h * 64 + dn * 16 + c] = (bf16)(oacc[dn][i] * inv);
    }
  }
#undef STAGE
}

// ---------------- launch ----------------
extern "C" void kernel_launch(void* const* d_in, const int* in_sizes, int n_in,
                              void* d_out, int out_size, void* d_ws, size_t ws_size,
                              hipStream_t stream) {
  const float* x  = (const float*)d_in[0];
  const float* Wq = (const float*)d_in[1];
  const float* Wk = (const float*)d_in[2];
  const float* Wv = (const float*)d_in[3];
  const float* Wo = (const float*)d_in[4];
  const float* bo = (const float*)d_in[5];
  float* out = (float*)d_out;
  char* ws = (char*)d_ws;

  bf16* Xb    = (bf16*)(ws);
  bf16* WqkvT = (bf16*)(ws + 16777216);
  bf16* WoT   = (bf16*)(ws + 23068672);
  bf16* QKV   = (bf16*)(ws + 25165824);
  bf16* VT    = (bf16*)(ws + 75497472);
  bf16* AttnO = (bf16*)(ws + 92274688);

  pack_x_kernel<<<8192, 256, 0, stream>>>(x, Xb);
  pack_wqkv_kernel<<<12288, 256, 0, stream>>>(Wq, Wk, Wv, WqkvT);
  pack_wo_kernel<<<4096, 256, 0, stream>>>(Wo, WoT);
  gemm5_kernel<false><<<768, 512, 0, stream>>>(Xb, WqkvT, QKV, nullptr, nullptr,
                                               3072, 1024);
  transpose_v_kernel<<<dim3(32, 64), 256, 0, stream>>>(QKV, VT);
  attn_kernel<<<512, 512, 0, stream>>>(QKV, VT, AttnO);
  gemm5_kernel<true><<<256, 512, 0, stream>>>(AttnO, WoT, nullptr, out, bo,
                                              1024, 1024);
}

// Round 14
// 178.666 us; speedup vs baseline: 1.0428x; 1.0428x over previous
//
#include <hip/hip_runtime.h>

// B=4, S=2048, D=1024, H=16, HS=64. Full bf16-MFMA pipeline.
// Workspace layout (needs ~104 MiB):
//   Xb     @ 0         : x as bf16            [8192][1024]   16 MiB
//   WqkvT  @ 16777216  : qkv weights B^T bf16 [3072][1024]    6 MiB
//   WoT    @ 23068672  : Wo^T bf16            [1024][1024]    2 MiB
//   QKV    @ 25165824  : Q|K|V bf16           [8192][3072]   48 MiB
//   VT     @ 75497472  : V^T bf16, kappa-ordered keys  [64bh][64][2048] 16 MiB
//   AttnO  @ 92274688  : attention out bf16   [8192][1024]   16 MiB

typedef __bf16 bf16;
typedef bf16 bf16x8 __attribute__((ext_vector_type(8)));
typedef bf16 bf16x4 __attribute__((ext_vector_type(4)));
typedef float f32x4 __attribute__((ext_vector_type(4)));

__device__ __forceinline__ void gload16(const void* gsrc, void* ldst) {
  __builtin_amdgcn_global_load_lds(
      (const __attribute__((address_space(1))) unsigned int*)gsrc,
      (__attribute__((address_space(3))) unsigned int*)ldst, 16, 0, 0);
}

__device__ __forceinline__ f32x4 mfma16(bf16x8 a, bf16x8 b, f32x4 c) {
  return __builtin_amdgcn_mfma_f32_16x16x32_bf16(a, b, c, 0, 0, 0);
}

// ---------------- pack kernels ----------------
__global__ __launch_bounds__(256) void pack_x_kernel(const float* __restrict__ x,
                                                     bf16* __restrict__ xb) {
  int i = (blockIdx.x * 256 + threadIdx.x) * 4;  // grid sized exactly
  float4 v = *(const float4*)(x + i);
  bf16x4 o;
  o[0] = (bf16)v.x; o[1] = (bf16)v.y; o[2] = (bf16)v.z; o[3] = (bf16)v.w;
  *(bf16x4*)(xb + i) = o;
}

// WT[n][k] = W{q,k,v}[h = (n%1024)/64][k][e = n%64], n in [0,3072)
__global__ __launch_bounds__(256) void pack_wqkv_kernel(const float* __restrict__ Wq,
                                                        const float* __restrict__ Wk,
                                                        const float* __restrict__ Wv,
                                                        bf16* __restrict__ WT) {
  int idx = blockIdx.x * 256 + threadIdx.x;  // 0..3145727
  int n = idx >> 10, k = idx & 1023;
  int sel = n >> 10, nn = n & 1023;
  const float* W = (sel == 0) ? Wq : (sel == 1 ? Wk : Wv);
  int h = nn >> 6, e = nn & 63;
  WT[(size_t)n * 1024 + k] = (bf16)W[h * 65536 + k * 64 + e];
}

// WoT[n][k] = Wo[k][n]
__global__ __launch_bounds__(256) void pack_wo_kernel(const float* __restrict__ Wo,
                                                      bf16* __restrict__ WoT) {
  int idx = blockIdx.x * 256 + threadIdx.x;  // 0..1048575
  int n = idx >> 10, k = idx & 1023;
  WoT[idx] = (bf16)Wo[k * 1024 + n];
}

// ---------------- GEMM v6: C[M][N] = A[M][K] * BT[N][K]^T ----------------
// r13 post-mortem: gemm5 (1 block/CU, coarse deep pipeline) regressed --
// m196's "coarse phase-split hurts" reproduced. The working lever is m114's
// cross-block overlap: co-resident blocks fill each other's barrier/vmcnt
// drains. gemm4 had only 2 blocks/CU (64KB). v6 = gemm4 at BK=32: LDS
// 2 slots x 16KB = 32KB -> 4 blocks/CU (VGPR ~75 -> 4 waves/SIMD), 50%
// occupancy. Per-wave still 64x64 (8 ds_read_b128 : 16 MFMA = 32 FLOP/B).
// BK=32 swizzle note: row stride is 64B (4 chunk slots), so the 3-bit XOR
// degrades; correct involution is chunk ^= (row>>1)&3 -> effective slot
// (row&1)*4+(g^((row>>1)&3)): 8 slots x 2 lanes = 2-way = free.
// One barrier + one vmcnt(0) per K-tile; n-major-per-XCD mapping.
template <bool F32OUT>
__global__ __launch_bounds__(256, 4) void gemm6_kernel(const bf16* __restrict__ A,
                                                       const bf16* __restrict__ BT,
                                                       bf16* __restrict__ Cb,
                                                       float* __restrict__ Cf,
                                                       const float* __restrict__ bias,
                                                       int N, int K) {
  __shared__ bf16 As[2][128 * 32];  // [slot][row][k], chunk-swizzled, 8KB
  __shared__ bf16 Bs[2][128 * 32];
  const int tid = threadIdx.x, lane = tid & 63, wave = tid >> 6;
  const int g = lane >> 4, c = lane & 15;
  const int wr = wave >> 1, wc = wave & 1;
  const int bid = blockIdx.x;
  const int xcd = bid & 7, local = bid >> 3;
  const int m0 = (xcd * 8 + (local & 7)) * 128;
  const int n0 = (local >> 3) * 128;

  // stage: thread covers LDS offset o = j*4096 + tid*16; row = j*64+(tid>>2),
  // slot = tid&3; fetch global chunk sch = slot ^ ((row>>1)&3)
  const int sch = (tid & 3) ^ ((tid >> 3) & 3);

#define STAGE6(T, S)                                                      \
  do {                                                                    \
    _Pragma("unroll") for (int j = 0; j < 2; ++j) {                       \
      const int r = j * 64 + (tid >> 2);                                  \
      const int ldso = j * 4096 + tid * 16;                               \
      gload16(A + (size_t)(m0 + r) * K + (T)*32 + sch * 8,                \
              (char*)&As[S][0] + ldso);                                   \
      gload16(BT + (size_t)(n0 + r) * K + (T)*32 + sch * 8,               \
              (char*)&Bs[S][0] + ldso);                                   \
    }                                                                     \
  } while (0)

  f32x4 acc[4][4] = {};
  const int nt = K >> 5;  // K-tiles of 32
  STAGE6(0, 0);
  asm volatile("s_waitcnt vmcnt(0)" ::: "memory");
  __builtin_amdgcn_sched_barrier(0);
  __builtin_amdgcn_s_barrier();
  __builtin_amdgcn_sched_barrier(0);

#pragma unroll 1
  for (int t = 0; t < nt; ++t) {
    const int s = t & 1;
    if (t + 1 < nt) STAGE6(t + 1, s ^ 1);
    bf16x8 af[4], bfr[4];
#pragma unroll
    for (int m = 0; m < 4; ++m) {
      const int row = wr * 64 + m * 16 + c;
      af[m] = *(const bf16x8*)((const char*)&As[s][0] + row * 64 +
                               ((g ^ ((row >> 1) & 3)) << 4));
    }
#pragma unroll
    for (int n = 0; n < 4; ++n) {
      const int row = wc * 64 + n * 16 + c;
      bfr[n] = *(const bf16x8*)((const char*)&Bs[s][0] + row * 64 +
                                ((g ^ ((row >> 1) & 3)) << 4));
    }
    // no lgkm drain: compiler interleaves reads/MFMAs with counted lgkmcnt
    __builtin_amdgcn_s_setprio(1);
#pragma unroll
    for (int m = 0; m < 4; ++m)
#pragma unroll
      for (int n = 0; n < 4; ++n)
        acc[m][n] = mfma16(af[m], bfr[n], acc[m][n]);
    __builtin_amdgcn_s_setprio(0);
    if (t + 1 < nt) {
      asm volatile("s_waitcnt vmcnt(0)" ::: "memory");  // next slot landed
      __builtin_amdgcn_sched_barrier(0);
      __builtin_amdgcn_s_barrier();
      __builtin_amdgcn_sched_barrier(0);
    }
  }
#undef STAGE6
  // epilogue (r7-verified mapping)
#pragma unroll
  for (int m = 0; m < 4; ++m)
#pragma unroll
    for (int n = 0; n < 4; ++n)
#pragma unroll
      for (int i = 0; i < 4; ++i) {
        int row = m0 + wr * 64 + m * 16 + g * 4 + i;
        int col = n0 + wc * 64 + n * 16 + c;
        if (F32OUT)
          Cf[(size_t)row * N + col] = acc[m][n][i] + bias[col];
        else
          Cb[(size_t)row * N + col] = (bf16)acc[m][n][i];
      }
}

// ---------------- V transpose: VT[bh][d][pos] with kappa-ordered keys ------
// Within each 32-key block, storage position p = g*8+j holds key
// kappa(p) = (j<4 ? 4g+j : 16+4g+(j-4)) -- exactly the PV B-frag order, so
// attn's V-read becomes ONE ds_read_b128 per (kss,dn) with even bank spread.
__global__ __launch_bounds__(256) void transpose_v_kernel(const bf16* __restrict__ qkv,
                                                          bf16* __restrict__ vt) {
  __shared__ bf16 tl[64][72];  // stride 144B keeps 16B alignment for b128 stores
  const int tid = threadIdx.x;
  const int st = blockIdx.x, bh = blockIdx.y;
  const int b = bh >> 4, h = bh & 15;
#pragma unroll
  for (int it = 0; it < 2; ++it) {
    int idx = it * 256 + tid;          // 0..511
    int sl = idx >> 3, ch = idx & 7;   // sl 0..63 (s row), ch 0..7 (d chunk)
    bf16x8 v = *(const bf16x8*)(qkv + (size_t)(b * 2048 + st * 64 + sl) * 3072 + 2048 + h * 64 + ch * 8);
    *(bf16x8*)&tl[sl][ch * 8] = v;
  }
  __syncthreads();
#pragma unroll
  for (int it = 0; it < 2; ++it) {
    int idx = it * 256 + tid;
    int d = idx >> 3, ch = idx & 7;    // d 0..63, output chunk 0..7 (8 keys)
    const int blk = ch >> 2, g = ch & 3;  // 32-key block, frag group
    bf16x8 o;
#pragma unroll
    for (int j = 0; j < 8; ++j) {
      int loc = (j < 4) ? (4 * g + j) : (16 + 4 * g + (j - 4));  // kappa
      o[j] = tl[blk * 32 + loc][d];
    }
    *(bf16x8*)(vt + ((size_t)bh * 64 + d) * 2048 + st * 64 + ch * 8) = o;
  }
}

// ---------------- causal flash attention ----------------
// Grid = 512 blocks x 512 threads (8 waves, 16 q-rows/wave), KVBLK=128.
// bh-major XCD mapping (K/V L2-resident per XCD). Block does qt=x then 15-x:
// 17 uniform K-tiles. Double-buffered staging, counted vmcnt. Swapped QK^T
// (mfma(K,Q)): per-lane softmax (q=c), in-lane PV A-frags, row-sum via
// ones-MFMA. Kappa-ordered VT -> single b128 V-reads, conflict-free.
// Tree-max + defer-max (T13, THR=8) cut the softmax VALU/serial chains.
__global__ __launch_bounds__(512, 4) void attn_kernel(const bf16* __restrict__ qkv,
                                                      const bf16* __restrict__ vt,
                                                      bf16* __restrict__ attn_out) {
  __shared__ bf16 Ks[2][128 * 64];   // [key][hd], chunk-swizzled, 16KB each
  __shared__ bf16 Vs[2][64 * 128];   // [d][kpos], chunk-swizzled, 16KB each
  const int tid = threadIdx.x, lane = tid & 63, wave = tid >> 6;
  const int g = lane >> 4, c = lane & 15;
  const int bid = blockIdx.x;
  const int xcd = bid & 7;
  const int x = (bid >> 3) & 7;
  const int bh = (bid >> 6) * 8 + xcd;
  const int b = bh >> 4, h = bh & 15;
  const float SCL = 0.125f * 1.4426950408889634f;  // log2(e) * scale

  bf16x8 ones;
#pragma unroll
  for (int j = 0; j < 8; ++j) ones[j] = (bf16)1.0f;

#define STAGE(KT, BUF)                                                                    \
  do {                                                                                    \
    _Pragma("unroll") for (int t2 = 0; t2 < 2; ++t2) {                                    \
      int o = t2 * 8192 + wave * 1024 + lane * 16; /* 0..16383 */                         \
      int rK = o >> 7, chK = (((o & 127) >> 4) ^ (rK & 7));                               \
      gload16((const char*)qkv +                                                          \
                  ((size_t)(b * 2048 + (KT)*128 + rK) * 3072 + 1024 + h * 64) * 2 +       \
                  (chK << 4),                                                             \
              (char*)Ks[BUF] + o);                                                        \
      int rV = o >> 8, chV = (((o & 255) >> 4) ^ (rV & 7));                               \
      gload16((const char*)vt + (((size_t)bh * 64 + rV) * 2048 + (KT)*128) * 2 +          \
                  (chV << 4),                                                             \
              (char*)Vs[BUF] + o);                                                        \
    }                                                                                     \
  } while (0)

#pragma unroll 1
  for (int ph = 0; ph < 2; ++ph) {
    const int qt = ph ? (15 - x) : x;
    const int qlow = qt * 128 + wave * 16;  // lowest q row of this wave

    bf16x8 qf[2];
#pragma unroll
    for (int kk = 0; kk < 2; ++kk) {
      size_t row = (size_t)(b * 2048 + qlow + c);
      qf[kk] = *(const bf16x8*)(qkv + row * 3072 + h * 64 + kk * 32 + g * 8);
    }

    f32x4 oacc[4] = {};
    f32x4 lacc = {};        // row-sums, oacc layout (q = qlow + 4g+i)
    float mrun = -3.0e38f;  // per-lane: q = qlow + c

    const int nkt = qt + 1;
    STAGE(0, 0);  // prologue
    for (int kt = 0; kt < nkt; ++kt) {
      const int cur = kt & 1;
      if (kt + 1 < nkt) {
        STAGE(kt + 1, cur ^ 1);
        asm volatile("s_waitcnt vmcnt(4)" ::: "memory");  // current tile landed
      } else {
        asm volatile("s_waitcnt vmcnt(0)" ::: "memory");
      }
      __builtin_amdgcn_sched_barrier(0);
      __builtin_amdgcn_s_barrier();
      __builtin_amdgcn_sched_barrier(0);
      // QK^T swapped: sc[n] holds S[key = kt*128+n*16+4g+i][q = qlow+c]
      f32x4 sc[8] = {};
      __builtin_amdgcn_s_setprio(1);
#pragma unroll
      for (int n = 0; n < 8; ++n) {
        int key = n * 16 + c;
#pragma unroll
        for (int kk = 0; kk < 2; ++kk) {
          bf16x8 kf = *(const bf16x8*)((const char*)Ks[cur] + key * 128 +
                                       (((kk * 4 + g) ^ (key & 7)) << 4));
          sc[n] = mfma16(kf, qf[kk], sc[n]);
        }
      }
      __builtin_amdgcn_s_setprio(0);
      const int q = qlow + c;
      if (kt == qt) {  // diagonal tile: causal mask
#pragma unroll
        for (int n = 0; n < 8; ++n)
#pragma unroll
          for (int i = 0; i < 4; ++i)
            sc[n][i] = ((kt * 128 + n * 16 + 4 * g + i) <= q) ? sc[n][i] : -3.0e38f;
      }
      // tree max (depth ~5 instead of a 32-deep serial chain)
      float vmax;
      {
        float a[8];
#pragma unroll
        for (int n = 0; n < 8; ++n)
          a[n] = fmaxf(fmaxf(sc[n][0], sc[n][1]), fmaxf(sc[n][2], sc[n][3]));
        float b0 = fmaxf(a[0], a[1]), b1 = fmaxf(a[2], a[3]);
        float b2 = fmaxf(a[4], a[5]), b3 = fmaxf(a[6], a[7]);
        vmax = fmaxf(fmaxf(b0, b1), fmaxf(b2, b3));
      }
      vmax = fmaxf(vmax, __shfl_xor(vmax, 16));
      vmax = fmaxf(vmax, __shfl_xor(vmax, 32));
      const float mx = vmax * SCL;
      // defer-max (T13): only rescale when the running max grew by >8 in
      // log2 domain; otherwise keep mrun (P bounded by 2^8, fp32-safe).
      if (!__all(mx <= mrun + 8.0f)) {
        const float mnew = fmaxf(mrun, mx);
        const float fs = __builtin_amdgcn_exp2f(mrun - mnew);
        mrun = mnew;
#pragma unroll
        for (int i = 0; i < 4; ++i) {
          float fsb = __shfl(fs, ((lane >> 4) << 2) + i);
          lacc[i] *= fsb;
#pragma unroll
          for (int dn = 0; dn < 4; ++dn) oacc[dn][i] *= fsb;
        }
      }
#pragma unroll
      for (int n = 0; n < 8; ++n)
#pragma unroll
        for (int i = 0; i < 4; ++i)
          sc[n][i] = __builtin_amdgcn_exp2f(fmaf(sc[n][i], SCL, -mrun));
      // pack PV A-frags: key = kss*32 + (j<4 ? 4g+j : 16+4g+(j-4))
      bf16x8 pa[4];
#pragma unroll
      for (int kss = 0; kss < 4; ++kss) {
        bf16x8 t;
#pragma unroll
        for (int j = 0; j < 4; ++j) t[j] = (bf16)sc[2 * kss][j];
#pragma unroll
        for (int j = 0; j < 4; ++j) t[4 + j] = (bf16)sc[2 * kss + 1][j];
        pa[kss] = t;
      }
      // PV + row-sum via ones-MFMA; kappa-ordered Vs -> one b128 per (kss,dn)
      __builtin_amdgcn_s_setprio(1);
#pragma unroll
      for (int kss = 0; kss < 4; ++kss) {
        lacc = mfma16(pa[kss], ones, lacc);
#pragma unroll
        for (int dn = 0; dn < 4; ++dn) {
          const int d = dn * 16 + c;
          bf16x8 vb = *(const bf16x8*)((const char*)Vs[cur] + d * 256 +
                                       (((kss * 4 + g) ^ (d & 7)) << 4));
          oacc[dn] = mfma16(pa[kss], vb, oacc[dn]);
        }
      }
      __builtin_amdgcn_s_setprio(0);
      __builtin_amdgcn_sched_barrier(0);
      __builtin_amdgcn_s_barrier();  // readers done before next-tile overwrite
      __builtin_amdgcn_sched_barrier(0);
    }
    // epilogue: normalize, store bf16 [8192][1024]
#pragma unroll
    for (int i = 0; i < 4; ++i) {
      float inv = __builtin_amdgcn_rcpf(lacc[i]);
      size_t row = (size_t)(b * 2048 + qlow + 4 * g + i);
#pragma unroll
      for (int dn = 0; dn < 4; ++dn)
        attn_out[row * 1024 + h * 64 + dn * 16 + c] = (bf16)(oacc[dn][i] * inv);
    }
  }
#undef STAGE
}

// ---------------- launch ----------------
extern "C" void kernel_launch(void* const* d_in, const int* in_sizes, int n_in,
                              void* d_out, int out_size, void* d_ws, size_t ws_size,
                              hipStream_t stream) {
  const float* x  = (const float*)d_in[0];
  const float* Wq = (const float*)d_in[1];
  const float* Wk = (const float*)d_in[2];
  const float* Wv = (const float*)d_in[3];
  const float* Wo = (const float*)d_in[4];
  const float* bo = (const float*)d_in[5];
  float* out = (float*)d_out;
  char* ws = (char*)d_ws;

  bf16* Xb    = (bf16*)(ws);
  bf16* WqkvT = (bf16*)(ws + 16777216);
  bf16* WoT   = (bf16*)(ws + 23068672);
  bf16* QKV   = (bf16*)(ws + 25165824);
  bf16* VT    = (bf16*)(ws + 75497472);
  bf16* AttnO = (bf16*)(ws + 92274688);

  pack_x_kernel<<<8192, 256, 0, stream>>>(x, Xb);
  pack_wqkv_kernel<<<12288, 256, 0, stream>>>(Wq, Wk, Wv, WqkvT);
  pack_wo_kernel<<<4096, 256, 0, stream>>>(Wo, WoT);
  gemm6_kernel<false><<<1536, 256, 0, stream>>>(Xb, WqkvT, QKV, nullptr, nullptr,
                                                3072, 1024);
  transpose_v_kernel<<<dim3(32, 64), 256, 0, stream>>>(QKV, VT);
  attn_kernel<<<512, 512, 0, stream>>>(QKV, VT, AttnO);
  gemm6_kernel<true><<<512, 256, 0, stream>>>(AttnO, WoT, nullptr, out, bo,
                                              1024, 1024);
}

// Round 15
// 167.482 us; speedup vs baseline: 1.1124x; 1.0668x over previous
//
#include <hip/hip_runtime.h>

// B=4, S=2048, D=1024, H=16, HS=64. Full bf16-MFMA pipeline.
// Workspace layout (needs ~104 MiB):
//   Xb     @ 0         : x as bf16            [8192][1024]   16 MiB
//   WqkvT  @ 16777216  : qkv weights B^T bf16 [3072][1024]    6 MiB
//   WoT    @ 23068672  : Wo^T bf16            [1024][1024]    2 MiB
//   QKV    @ 25165824  : Q|K|V bf16           [8192][3072]   48 MiB
//   VT     @ 75497472  : V^T bf16, kappa-ordered keys  [64bh][64][2048] 16 MiB
//   AttnO  @ 92274688  : attention out bf16   [8192][1024]   16 MiB

typedef __bf16 bf16;
typedef bf16 bf16x8 __attribute__((ext_vector_type(8)));
typedef bf16 bf16x4 __attribute__((ext_vector_type(4)));
typedef float f32x4 __attribute__((ext_vector_type(4)));

__device__ __forceinline__ void gload16(const void* gsrc, void* ldst) {
  __builtin_amdgcn_global_load_lds(
      (const __attribute__((address_space(1))) unsigned int*)gsrc,
      (__attribute__((address_space(3))) unsigned int*)ldst, 16, 0, 0);
}

__device__ __forceinline__ f32x4 mfma16(bf16x8 a, bf16x8 b, f32x4 c) {
  return __builtin_amdgcn_mfma_f32_16x16x32_bf16(a, b, c, 0, 0, 0);
}

// ---------------- fused pack kernel (one launch) ----------------
__global__ __launch_bounds__(256) void pack_all_kernel(const float* __restrict__ x,
                                                       const float* __restrict__ Wq,
                                                       const float* __restrict__ Wk,
                                                       const float* __restrict__ Wv,
                                                       const float* __restrict__ Wo,
                                                       bf16* __restrict__ xb,
                                                       bf16* __restrict__ WT,
                                                       bf16* __restrict__ WoT) {
  const int stride = gridDim.x * 256;
  const int t0 = blockIdx.x * 256 + threadIdx.x;
  // x -> bf16, 2097152 float4 groups
  for (int i = t0; i < 2097152; i += stride) {
    float4 v = *(const float4*)(x + (size_t)i * 4);
    bf16x4 o;
    o[0] = (bf16)v.x; o[1] = (bf16)v.y; o[2] = (bf16)v.z; o[3] = (bf16)v.w;
    *(bf16x4*)(xb + (size_t)i * 4) = o;
  }
  // WT[n][k] = W{q,k,v}[h=(n%1024)/64][k][e=n%64], n in [0,3072)
  for (int idx = t0; idx < 3145728; idx += stride) {
    int n = idx >> 10, k = idx & 1023;
    int sel = n >> 10, nn = n & 1023;
    const float* W = (sel == 0) ? Wq : (sel == 1 ? Wk : Wv);
    int h = nn >> 6, e = nn & 63;
    WT[(size_t)n * 1024 + k] = (bf16)W[h * 65536 + k * 64 + e];
  }
  // WoT[n][k] = Wo[k][n]
  for (int idx = t0; idx < 1048576; idx += stride) {
    int n = idx >> 10, k = idx & 1023;
    WoT[idx] = (bf16)Wo[k * 1024 + n];
  }
}

// ---------------- GEMM v4 (r12 best: 69.6us): C = A * BT^T ----------------
// Per-wave 64x64 (32 FLOP per LDS byte), BM=BN=128, BK=64, 256 threads
// (4 waves 2x2), 2 LDS slots (64KB) -> 2 blocks/CU. One barrier + one
// vmcnt(0) per K-tile. 3-bit XOR chunk swizzle. n-major-per-XCD mapping.
// No lgkm fence between ds_reads and MFMAs (compiler interleaves).
template <bool F32OUT>
__global__ __launch_bounds__(256, 2) void gemm4_kernel(const bf16* __restrict__ A,
                                                       const bf16* __restrict__ BT,
                                                       bf16* __restrict__ Cb,
                                                       float* __restrict__ Cf,
                                                       const float* __restrict__ bias,
                                                       int N, int K) {
  __shared__ bf16 As[2][128 * 64];  // [slot][row][k], chunk-swizzled
  __shared__ bf16 Bs[2][128 * 64];
  const int tid = threadIdx.x, lane = tid & 63, wave = tid >> 6;
  const int g = lane >> 4, c = lane & 15;
  const int wr = wave >> 1, wc = wave & 1;
  const int bid = blockIdx.x;
  const int xcd = bid & 7, local = bid >> 3;
  const int m0 = (xcd * 8 + (local & 7)) * 128;
  const int n0 = (local >> 3) * 128;

  const int schunk = (lane & 7) ^ (lane >> 3);  // source k-chunk for staging

#define STAGE4(T, S)                                                      \
  do {                                                                    \
    _Pragma("unroll") for (int j = 0; j < 4; ++j) {                       \
      const int r = wave * 32 + j * 8 + (lane >> 3);                      \
      const int ldso = wave * 4096 + j * 1024 + lane * 16;                \
      gload16(A + (size_t)(m0 + r) * K + (T)*64 + schunk * 8,             \
              (char*)&As[S][0] + ldso);                                   \
      gload16(BT + (size_t)(n0 + r) * K + (T)*64 + schunk * 8,            \
              (char*)&Bs[S][0] + ldso);                                   \
    }                                                                     \
  } while (0)

  f32x4 acc[4][4] = {};
  const int nt = K >> 6;  // K-tiles of 64
  STAGE4(0, 0);
  asm volatile("s_waitcnt vmcnt(0)" ::: "memory");
  __builtin_amdgcn_sched_barrier(0);
  __builtin_amdgcn_s_barrier();
  __builtin_amdgcn_sched_barrier(0);

#pragma unroll 1
  for (int t = 0; t < nt; ++t) {
    const int s = t & 1;
    if (t + 1 < nt) STAGE4(t + 1, s ^ 1);
    bf16x8 af[4][2], bfr[4][2];
#pragma unroll
    for (int m = 0; m < 4; ++m) {
      const int row = wr * 64 + m * 16 + c;
#pragma unroll
      for (int kk = 0; kk < 2; ++kk)
        af[m][kk] = *(const bf16x8*)((const char*)&As[s][0] + row * 128 +
                                     (((kk * 4 + g) ^ (row & 7)) << 4));
    }
#pragma unroll
    for (int n = 0; n < 4; ++n) {
      const int row = wc * 64 + n * 16 + c;
#pragma unroll
      for (int kk = 0; kk < 2; ++kk)
        bfr[n][kk] = *(const bf16x8*)((const char*)&Bs[s][0] + row * 128 +
                                      (((kk * 4 + g) ^ (row & 7)) << 4));
    }
    // no lgkm drain: compiler interleaves reads/MFMAs with counted lgkmcnt
    __builtin_amdgcn_s_setprio(1);
#pragma unroll
    for (int kk = 0; kk < 2; ++kk)
#pragma unroll
      for (int m = 0; m < 4; ++m)
#pragma unroll
        for (int n = 0; n < 4; ++n)
          acc[m][n] = mfma16(af[m][kk], bfr[n][kk], acc[m][n]);
    __builtin_amdgcn_s_setprio(0);
    if (t + 1 < nt) {
      asm volatile("s_waitcnt vmcnt(0)" ::: "memory");  // next slot landed
      __builtin_amdgcn_sched_barrier(0);
      __builtin_amdgcn_s_barrier();
      __builtin_amdgcn_sched_barrier(0);
    }
  }
#undef STAGE4
  // epilogue (r7-verified mapping)
#pragma unroll
  for (int m = 0; m < 4; ++m)
#pragma unroll
    for (int n = 0; n < 4; ++n)
#pragma unroll
      for (int i = 0; i < 4; ++i) {
        int row = m0 + wr * 64 + m * 16 + g * 4 + i;
        int col = n0 + wc * 64 + n * 16 + c;
        if (F32OUT)
          Cf[(size_t)row * N + col] = acc[m][n][i] + bias[col];
        else
          Cb[(size_t)row * N + col] = (bf16)acc[m][n][i];
      }
}

// ---------------- V transpose: VT[bh][d][pos] with kappa-ordered keys ------
__global__ __launch_bounds__(256) void transpose_v_kernel(const bf16* __restrict__ qkv,
                                                          bf16* __restrict__ vt) {
  __shared__ bf16 tl[64][72];  // stride 144B keeps 16B alignment for b128 stores
  const int tid = threadIdx.x;
  const int st = blockIdx.x, bh = blockIdx.y;
  const int b = bh >> 4, h = bh & 15;
#pragma unroll
  for (int it = 0; it < 2; ++it) {
    int idx = it * 256 + tid;          // 0..511
    int sl = idx >> 3, ch = idx & 7;   // sl 0..63 (s row), ch 0..7 (d chunk)
    bf16x8 v = *(const bf16x8*)(qkv + (size_t)(b * 2048 + st * 64 + sl) * 3072 + 2048 + h * 64 + ch * 8);
    *(bf16x8*)&tl[sl][ch * 8] = v;
  }
  __syncthreads();
#pragma unroll
  for (int it = 0; it < 2; ++it) {
    int idx = it * 256 + tid;
    int d = idx >> 3, ch = idx & 7;    // d 0..63, output chunk 0..7 (8 keys)
    const int blk = ch >> 2, g = ch & 3;  // 32-key block, frag group
    bf16x8 o;
#pragma unroll
    for (int j = 0; j < 8; ++j) {
      int loc = (j < 4) ? (4 * g + j) : (16 + 4 * g + (j - 4));  // kappa
      o[j] = tl[blk * 32 + loc][d];
    }
    *(bf16x8*)(vt + ((size_t)bh * 64 + d) * 2048 + st * 64 + ch * 8) = o;
  }
}

// ---------------- causal flash attention ----------------
// Grid = 512 blocks x 512 threads (8 waves, 16 q-rows/wave), KVBLK=128.
// bh-major XCD mapping (K/V L2-resident per XCD). Block does qt=x then 15-x.
// r15 sync restructure (gemm4's proven single-barrier skeleton): per tile
// { stage(kt+1); compute(kt); vmcnt(0); barrier } -- ONE barrier per tile
// (was 2), and the vmcnt drain sits AFTER compute (loads had ~2000cy to
// land -> free). Stage is issued after the previous barrier, so the prior
// readers of the re-staged buffer are provably done. A phase-boundary
// barrier protects buf0 from the previous phase's last-tile readers.
__global__ __launch_bounds__(512, 4) void attn_kernel(const bf16* __restrict__ qkv,
                                                      const bf16* __restrict__ vt,
                                                      bf16* __restrict__ attn_out) {
  __shared__ bf16 Ks[2][128 * 64];   // [key][hd], chunk-swizzled, 16KB each
  __shared__ bf16 Vs[2][64 * 128];   // [d][kpos], chunk-swizzled, 16KB each
  const int tid = threadIdx.x, lane = tid & 63, wave = tid >> 6;
  const int g = lane >> 4, c = lane & 15;
  const int bid = blockIdx.x;
  const int xcd = bid & 7;
  const int x = (bid >> 3) & 7;
  const int bh = (bid >> 6) * 8 + xcd;
  const int b = bh >> 4, h = bh & 15;
  const float SCL = 0.125f * 1.4426950408889634f;  // log2(e) * scale

  bf16x8 ones;
#pragma unroll
  for (int j = 0; j < 8; ++j) ones[j] = (bf16)1.0f;

#define STAGE(KT, BUF)                                                                    \
  do {                                                                                    \
    _Pragma("unroll") for (int t2 = 0; t2 < 2; ++t2) {                                    \
      int o = t2 * 8192 + wave * 1024 + lane * 16; /* 0..16383 */                         \
      int rK = o >> 7, chK = (((o & 127) >> 4) ^ (rK & 7));                               \
      gload16((const char*)qkv +                                                          \
                  ((size_t)(b * 2048 + (KT)*128 + rK) * 3072 + 1024 + h * 64) * 2 +       \
                  (chK << 4),                                                             \
              (char*)Ks[BUF] + o);                                                        \
      int rV = o >> 8, chV = (((o & 255) >> 4) ^ (rV & 7));                               \
      gload16((const char*)vt + (((size_t)bh * 64 + rV) * 2048 + (KT)*128) * 2 +          \
                  (chV << 4),                                                             \
              (char*)Vs[BUF] + o);                                                        \
    }                                                                                     \
  } while (0)

#pragma unroll 1
  for (int ph = 0; ph < 2; ++ph) {
    const int qt = ph ? (15 - x) : x;
    const int qlow = qt * 128 + wave * 16;  // lowest q row of this wave

    bf16x8 qf[2];
#pragma unroll
    for (int kk = 0; kk < 2; ++kk) {
      size_t row = (size_t)(b * 2048 + qlow + c);
      qf[kk] = *(const bf16x8*)(qkv + row * 3072 + h * 64 + kk * 32 + g * 8);
    }

    f32x4 oacc[4] = {};
    f32x4 lacc = {};        // row-sums, oacc layout (q = qlow + 4g+i)
    float mrun = -3.0e38f;  // per-lane: q = qlow + c

    const int nkt = qt + 1;
    // phase prologue: protect buf0 from prev phase's last-tile readers,
    // then stage tile 0 and publish it.
    __builtin_amdgcn_s_barrier();
    __builtin_amdgcn_sched_barrier(0);
    STAGE(0, 0);
    asm volatile("s_waitcnt vmcnt(0)" ::: "memory");
    __builtin_amdgcn_sched_barrier(0);
    __builtin_amdgcn_s_barrier();
    __builtin_amdgcn_sched_barrier(0);
    for (int kt = 0; kt < nkt; ++kt) {
      const int cur = kt & 1;
      if (kt + 1 < nkt) STAGE(kt + 1, cur ^ 1);
      // QK^T swapped: sc[n] holds S[key = kt*128+n*16+4g+i][q = qlow+c]
      f32x4 sc[8] = {};
      __builtin_amdgcn_s_setprio(1);
#pragma unroll
      for (int n = 0; n < 8; ++n) {
        int key = n * 16 + c;
#pragma unroll
        for (int kk = 0; kk < 2; ++kk) {
          bf16x8 kf = *(const bf16x8*)((const char*)Ks[cur] + key * 128 +
                                       (((kk * 4 + g) ^ (key & 7)) << 4));
          sc[n] = mfma16(kf, qf[kk], sc[n]);
        }
      }
      __builtin_amdgcn_s_setprio(0);
      const int q = qlow + c;
      if (kt == qt) {  // diagonal tile: causal mask
#pragma unroll
        for (int n = 0; n < 8; ++n)
#pragma unroll
          for (int i = 0; i < 4; ++i)
            sc[n][i] = ((kt * 128 + n * 16 + 4 * g + i) <= q) ? sc[n][i] : -3.0e38f;
      }
      // tree max (depth ~5 instead of a 32-deep serial chain)
      float vmax;
      {
        float a[8];
#pragma unroll
        for (int n = 0; n < 8; ++n)
          a[n] = fmaxf(fmaxf(sc[n][0], sc[n][1]), fmaxf(sc[n][2], sc[n][3]));
        float b0 = fmaxf(a[0], a[1]), b1 = fmaxf(a[2], a[3]);
        float b2 = fmaxf(a[4], a[5]), b3 = fmaxf(a[6], a[7]);
        vmax = fmaxf(fmaxf(b0, b1), fmaxf(b2, b3));
      }
      vmax = fmaxf(vmax, __shfl_xor(vmax, 16));
      vmax = fmaxf(vmax, __shfl_xor(vmax, 32));
      const float mx = vmax * SCL;
      // defer-max (T13): only rescale when the running max grew by >8 in
      // log2 domain; otherwise keep mrun (P bounded by 2^8, fp32-safe).
      if (!__all(mx <= mrun + 8.0f)) {
        const float mnew = fmaxf(mrun, mx);
        const float fs = __builtin_amdgcn_exp2f(mrun - mnew);
        mrun = mnew;
#pragma unroll
        for (int i = 0; i < 4; ++i) {
          float fsb = __shfl(fs, ((lane >> 4) << 2) + i);
          lacc[i] *= fsb;
#pragma unroll
          for (int dn = 0; dn < 4; ++dn) oacc[dn][i] *= fsb;
        }
      }
#pragma unroll
      for (int n = 0; n < 8; ++n)
#pragma unroll
        for (int i = 0; i < 4; ++i)
          sc[n][i] = __builtin_amdgcn_exp2f(fmaf(sc[n][i], SCL, -mrun));
      // pack PV A-frags: key = kss*32 + (j<4 ? 4g+j : 16+4g+(j-4))
      bf16x8 pa[4];
#pragma unroll
      for (int kss = 0; kss < 4; ++kss) {
        bf16x8 t;
#pragma unroll
        for (int j = 0; j < 4; ++j) t[j] = (bf16)sc[2 * kss][j];
#pragma unroll
        for (int j = 0; j < 4; ++j) t[4 + j] = (bf16)sc[2 * kss + 1][j];
        pa[kss] = t;
      }
      // PV + row-sum via ones-MFMA; kappa-ordered Vs -> one b128 per (kss,dn)
      __builtin_amdgcn_s_setprio(1);
#pragma unroll
      for (int kss = 0; kss < 4; ++kss) {
        lacc = mfma16(pa[kss], ones, lacc);
#pragma unroll
        for (int dn = 0; dn < 4; ++dn) {
          const int d = dn * 16 + c;
          bf16x8 vb = *(const bf16x8*)((const char*)Vs[cur] + d * 256 +
                                       (((kss * 4 + g) ^ (d & 7)) << 4));
          oacc[dn] = mfma16(pa[kss], vb, oacc[dn]);
        }
      }
      __builtin_amdgcn_s_setprio(0);
      if (kt + 1 < nkt) {
        asm volatile("s_waitcnt vmcnt(0)" ::: "memory");  // kt+1 landed (free: issued ~2000cy ago)
        __builtin_amdgcn_sched_barrier(0);
        __builtin_amdgcn_s_barrier();  // publish kt+1; readers of cur done
        __builtin_amdgcn_sched_barrier(0);
      }
    }
    // epilogue: normalize, store bf16 [8192][1024]
#pragma unroll
    for (int i = 0; i < 4; ++i) {
      float inv = __builtin_amdgcn_rcpf(lacc[i]);
      size_t row = (size_t)(b * 2048 + qlow + 4 * g + i);
#pragma unroll
      for (int dn = 0; dn < 4; ++dn)
        attn_out[row * 1024 + h * 64 + dn * 16 + c] = (bf16)(oacc[dn][i] * inv);
    }
  }
#undef STAGE
}

// ---------------- launch ----------------
extern "C" void kernel_launch(void* const* d_in, const int* in_sizes, int n_in,
                              void* d_out, int out_size, void* d_ws, size_t ws_size,
                              hipStream_t stream) {
  const float* x  = (const float*)d_in[0];
  const float* Wq = (const float*)d_in[1];
  const float* Wk = (const float*)d_in[2];
  const float* Wv = (const float*)d_in[3];
  const float* Wo = (const float*)d_in[4];
  const float* bo = (const float*)d_in[5];
  float* out = (float*)d_out;
  char* ws = (char*)d_ws;

  bf16* Xb    = (bf16*)(ws);
  bf16* WqkvT = (bf16*)(ws + 16777216);
  bf16* WoT   = (bf16*)(ws + 23068672);
  bf16* QKV   = (bf16*)(ws + 25165824);
  bf16* VT    = (bf16*)(ws + 75497472);
  bf16* AttnO = (bf16*)(ws + 92274688);

  pack_all_kernel<<<2048, 256, 0, stream>>>(x, Wq, Wk, Wv, Wo, Xb, WqkvT, WoT);
  gemm4_kernel<false><<<1536, 256, 0, stream>>>(Xb, WqkvT, QKV, nullptr, nullptr,
                                                3072, 1024);
  transpose_v_kernel<<<dim3(32, 64), 256, 0, stream>>>(QKV, VT);
  attn_kernel<<<512, 512, 0, stream>>>(QKV, VT, AttnO);
  gemm4_kernel<true><<<512, 256, 0, stream>>>(AttnO, WoT, nullptr, out, bo,
                                              1024, 1024);
}